// Round 3
// baseline (644.145 us; speedup 1.0000x reference)
//
#include <hip/hip_runtime.h>
#include <math.h>

#define D_MODEL 1024
#define N_HEADS 16
#define D_K 64
#define B_SZ 64
#define S_LEN 2048

// ---------------- kernel 0: qh[b,n] = q[b,:] @ Wq[:,n] + bq[n] ----------------
// grid 256 = (64 b x 4 n-chunks), block 256
__global__ __launch_bounds__(256) void k_qh(const float* __restrict__ q,
                                            const float* __restrict__ Wq,
                                            const float* __restrict__ bq,
                                            float* __restrict__ qh) {
    int b = blockIdx.x >> 2;
    int nc = blockIdx.x & 3;
    int t = threadIdx.x;
    __shared__ float ql[D_MODEL];
    ((float4*)ql)[t] = ((const float4*)(q + (size_t)b * D_MODEL))[t];
    __syncthreads();
    int n = nc * 256 + t;
    const float* w = Wq + n;
    float acc = 0.f;
#pragma unroll 8
    for (int d = 0; d < D_MODEL; ++d) acc = fmaf(ql[d], w[(size_t)d * D_MODEL], acc);
    qh[(size_t)b * D_MODEL + n] = acc + bq[n];
}

// ---------------- kernel 1: qt[b,h,d] = (1/8) * sum_j qh[b,h*64+j] * Wk[d, h*64+j] ----------------
// grid 1024 = (b,h), block 256; thread covers d = t + 256p
__global__ __launch_bounds__(256) void k_qtil(const float* __restrict__ qh,
                                              const float* __restrict__ Wk,
                                              float* __restrict__ qt) {
    int b = blockIdx.x >> 4;
    int h = blockIdx.x & 15;
    int t = threadIdx.x;
    __shared__ float qhl[D_K];
    if (t < 16) ((float4*)qhl)[t] = ((const float4*)(qh + (size_t)b * D_MODEL + h * D_K))[t];
    __syncthreads();
#pragma unroll
    for (int p = 0; p < 4; ++p) {
        int d = p * 256 + t;
        const float* w = Wk + (size_t)d * D_MODEL + h * D_K;
        float acc = 0.f;
#pragma unroll
        for (int j4 = 0; j4 < 16; ++j4) {
            float4 w4 = ((const float4*)w)[j4];
            float4 q4 = ((const float4*)qhl)[j4];
            acc += w4.x * q4.x + w4.y * q4.y + w4.z * q4.z + w4.w * q4.w;
        }
        qt[((size_t)(b * N_HEADS + h)) * D_MODEL + d] = acc * 0.125f;
    }
}

// ---------------- kernel 2: scores[b,h,s] = k[b,s,:] . qt[b,h,:] ----------------
// grid 512 = (64 b x 8 s-tiles of 256), block 256 = 4 waves.
// Round-0 mapping (wave w -> heads 4w..4w+3; lane owns s = s0+64i+lane, i<4; 4s x 4h reg tile)
// + double-buffered LDS (k tile AND qt tile), register prefetch, ONE barrier per dc-iter.
#define ST 256
#define DC 32
#define KROW 36  // 32 + 4 pad: conflict-free b128 reads (quad = 9*row % 8)
#define KTSZ (ST * KROW)
__global__ __launch_bounds__(256) void k_scores(const float* __restrict__ k,
                                                const float* __restrict__ qt,
                                                float* __restrict__ sc) {
    __shared__ float kt[2][KTSZ];          // 2 x 36 KB
    __shared__ float qtl[2][N_HEADS * DC]; // 2 x 2 KB   (total 77.8 KB -> 2 blocks/CU)
    int b = blockIdx.x >> 3;
    int st = blockIdx.x & 7;
    int t = threadIdx.x;
    int w = t >> 6, lane = t & 63;
    int s0 = st * ST;
    const float* kbase = k + ((size_t)b * S_LEN + s0) * D_MODEL;
    const float* qtbase = qt + (size_t)b * N_HEADS * D_MODEL;
    int ss = t >> 3, sd = t & 7;  // stage pattern: idx = t + 256p -> row ss+32p, col4 sd
    // ---- prologue: preload tile dc=0 into registers ----
    float4 kr[8];
#pragma unroll
    for (int p = 0; p < 8; ++p)
        kr[p] = *(const float4*)(kbase + (size_t)(ss + 32 * p) * D_MODEL + 4 * sd);
    float4 qr = make_float4(0.f, 0.f, 0.f, 0.f);
    int qh_ = t >> 3, qd = t & 7;  // t<128: head qh_, col4 qd
    if (t < 128) qr = *(const float4*)(qtbase + (size_t)qh_ * D_MODEL + 4 * qd);
    float acc[4][4] = {};
    int buf = 0;
    for (int dc = 0; dc < D_MODEL; dc += DC, buf ^= 1) {
        // ---- stage prefetched registers into LDS buffer `buf` ----
#pragma unroll
        for (int p = 0; p < 8; ++p)
            *(float4*)(&kt[buf][(ss + 32 * p) * KROW + 4 * sd]) = kr[p];
        if (t < 128) *(float4*)(&qtl[buf][qh_ * DC + 4 * qd]) = qr;
        __syncthreads();  // buf now valid; buf^1's last readers finished before barrier of prev iter
        // ---- issue next-tile global loads (consumed at next iter's stage-write) ----
        int dcn = dc + DC;
        if (dcn < D_MODEL) {
#pragma unroll
            for (int p = 0; p < 8; ++p)
                kr[p] = *(const float4*)(kbase + (size_t)(ss + 32 * p) * D_MODEL + dcn + 4 * sd);
            if (t < 128) qr = *(const float4*)(qtbase + (size_t)qh_ * D_MODEL + dcn + 4 * qd);
        }
        // ---- compute on buffer `buf` (round-0 inner loop) ----
#pragma unroll
        for (int d4 = 0; d4 < DC / 4; ++d4) {
            float4 qv[4], kv[4];
#pragma unroll
            for (int j = 0; j < 4; ++j) qv[j] = *(const float4*)(&qtl[buf][(4 * w + j) * DC + 4 * d4]);
#pragma unroll
            for (int i = 0; i < 4; ++i) kv[i] = *(const float4*)(&kt[buf][(64 * i + lane) * KROW + 4 * d4]);
#pragma unroll
            for (int i = 0; i < 4; ++i)
#pragma unroll
                for (int j = 0; j < 4; ++j)
                    acc[i][j] = fmaf(kv[i].x, qv[j].x,
                                fmaf(kv[i].y, qv[j].y,
                                fmaf(kv[i].z, qv[j].z,
                                fmaf(kv[i].w, qv[j].w, acc[i][j]))));
        }
        // no second barrier: next iter writes the other buffer (race-free by induction)
    }
#pragma unroll
    for (int j = 0; j < 4; ++j)
#pragma unroll
        for (int i = 0; i < 4; ++i)
            sc[((size_t)(b * N_HEADS + 4 * w + j)) * S_LEN + s0 + 64 * i + lane] = acc[i][j];
}

// ---------------- kernel 3: softmax in-place over s (row = b*16+h) ----------------
__global__ __launch_bounds__(256) void k_softmax(float* __restrict__ sc) {
    int row = blockIdx.x;
    int t = threadIdx.x;
    float4* p = (float4*)(sc + (size_t)row * S_LEN);
    float4 x0 = p[t];
    float4 x1 = p[t + 256];
    float m = fmaxf(fmaxf(fmaxf(x0.x, x0.y), fmaxf(x0.z, x0.w)),
                    fmaxf(fmaxf(x1.x, x1.y), fmaxf(x1.z, x1.w)));
#pragma unroll
    for (int o = 32; o; o >>= 1) m = fmaxf(m, __shfl_xor(m, o, 64));
    __shared__ float redm[4], reds[4];
    int w = t >> 6, lane = t & 63;
    if (lane == 0) redm[w] = m;
    __syncthreads();
    m = fmaxf(fmaxf(redm[0], redm[1]), fmaxf(redm[2], redm[3]));
    x0.x = __expf(x0.x - m); x0.y = __expf(x0.y - m);
    x0.z = __expf(x0.z - m); x0.w = __expf(x0.w - m);
    x1.x = __expf(x1.x - m); x1.y = __expf(x1.y - m);
    x1.z = __expf(x1.z - m); x1.w = __expf(x1.w - m);
    float s = x0.x + x0.y + x0.z + x0.w + x1.x + x1.y + x1.z + x1.w;
#pragma unroll
    for (int o = 32; o; o >>= 1) s += __shfl_xor(s, o, 64);
    if (lane == 0) reds[w] = s;
    __syncthreads();
    s = reds[0] + reds[1] + reds[2] + reds[3];
    float inv = 1.0f / s;
    x0.x *= inv; x0.y *= inv; x0.z *= inv; x0.w *= inv;
    x1.x *= inv; x1.y *= inv; x1.z *= inv; x1.w *= inv;
    p[t] = x0;
    p[t + 256] = x1;
}

// ---------------- kernel 4: part[ch,b,h,d] = sum_{s in chunk} attn[b,h,s] * v[b,s,d] ----------------
// grid 512 = (64 b x 8 s-chunks), block 256; thread owns d-float4; 16 head accums.
// Round-0 structure + explicit depth-1 register prefetch of the next 4 v-rows.
__global__ __launch_bounds__(256) void k_av(const float* __restrict__ v,
                                            const float* __restrict__ sc,
                                            float* __restrict__ part) {
    int b = blockIdx.x >> 3;
    int ch = blockIdx.x & 7;
    int t = threadIdx.x;
    int s0 = ch * 256;
    __shared__ float al[N_HEADS * 256];  // [h][s], 16 KB
#pragma unroll
    for (int p = 0; p < 4; ++p) {
        int idx = t + 256 * p;
        int h = idx >> 6, s4 = idx & 63;
        *(float4*)(al + h * 256 + 4 * s4) =
            *(const float4*)(sc + ((size_t)(b * N_HEADS + h)) * S_LEN + s0 + 4 * s4);
    }
    __syncthreads();
    float4 acc[N_HEADS];
#pragma unroll
    for (int h = 0; h < N_HEADS; ++h) acc[h] = make_float4(0.f, 0.f, 0.f, 0.f);
    const float* vbase = v + ((size_t)b * S_LEN + s0) * D_MODEL + 4 * t;
    // prologue: rows 0..3
    float4 c0 = *(const float4*)(vbase);
    float4 c1 = *(const float4*)(vbase + D_MODEL);
    float4 c2 = *(const float4*)(vbase + 2 * D_MODEL);
    float4 c3 = *(const float4*)(vbase + 3 * D_MODEL);
    for (int sg = 0; sg < 64; ++sg) {
        // prefetch next 4 rows (wrap: last iter reloads row 0 -> L1 hit, harmless)
        const float* np = vbase + (size_t)(4 * ((sg + 1) & 63)) * D_MODEL;
        float4 n0 = *(const float4*)(np);
        float4 n1 = *(const float4*)(np + D_MODEL);
        float4 n2 = *(const float4*)(np + 2 * D_MODEL);
        float4 n3 = *(const float4*)(np + 3 * D_MODEL);
#pragma unroll
        for (int h = 0; h < N_HEADS; ++h) {
            float4 a4 = *(const float4*)(al + h * 256 + 4 * sg);  // LDS broadcast (in-order returns)
            acc[h].x = fmaf(a4.x, c0.x, fmaf(a4.y, c1.x, fmaf(a4.z, c2.x, fmaf(a4.w, c3.x, acc[h].x))));
            acc[h].y = fmaf(a4.x, c0.y, fmaf(a4.y, c1.y, fmaf(a4.z, c2.y, fmaf(a4.w, c3.y, acc[h].y))));
            acc[h].z = fmaf(a4.x, c0.z, fmaf(a4.y, c1.z, fmaf(a4.z, c2.z, fmaf(a4.w, c3.z, acc[h].z))));
            acc[h].w = fmaf(a4.x, c0.w, fmaf(a4.y, c1.w, fmaf(a4.z, c2.w, fmaf(a4.w, c3.w, acc[h].w))));
        }
        c0 = n0; c1 = n1; c2 = n2; c3 = n3;
    }
#pragma unroll
    for (int h = 0; h < N_HEADS; ++h)
        *(float4*)(part + (((size_t)ch * B_SZ + b) * N_HEADS + h) * D_MODEL + 4 * t) = acc[h];
}

// ---------------- kernel 5: cc[b, h*64+j] = sum_d vt[b,h,d]*Wv[d,h*64+j] + bv ----------------
// grid 1024 = (b,h), block 64 (1 wave); vt = sum of 8 partials, staged in LDS
__global__ __launch_bounds__(64) void k_cc(const float* __restrict__ part,
                                           const float* __restrict__ Wv,
                                           const float* __restrict__ bv,
                                           float* __restrict__ cc) {
    int b = blockIdx.x >> 4, h = blockIdx.x & 15;
    int lane = threadIdx.x;
    __shared__ float vt[D_MODEL];
#pragma unroll
    for (int p = 0; p < 4; ++p) {
        int i4 = lane + 64 * p;
        float4 s = make_float4(0.f, 0.f, 0.f, 0.f);
#pragma unroll
        for (int ch = 0; ch < 8; ++ch) {
            float4 x = *(const float4*)(part + (((size_t)ch * B_SZ + b) * N_HEADS + h) * D_MODEL + 4 * i4);
            s.x += x.x; s.y += x.y; s.z += x.z; s.w += x.w;
        }
        *(float4*)(vt + 4 * i4) = s;
    }
    __syncthreads();
    const float* w = Wv + h * D_K + lane;
    float acc = 0.f;
#pragma unroll 8
    for (int d = 0; d < D_MODEL; ++d) acc = fmaf(vt[d], w[(size_t)d * D_MODEL], acc);
    cc[(size_t)b * D_MODEL + h * D_K + lane] = acc + bv[h * D_K + lane];
}

// ---------------- kernel 6: out[b,n] = relu(cc[b,:] @ Wo[:,n] + bo[n]) ----------------
// grid 256 = (64 b x 4 n-chunks), block 256
__global__ __launch_bounds__(256) void k_out(const float* __restrict__ cc,
                                             const float* __restrict__ Wo,
                                             const float* __restrict__ bo,
                                             float* __restrict__ out) {
    int b = blockIdx.x >> 2, nc = blockIdx.x & 3;
    int t = threadIdx.x;
    __shared__ float cl[D_MODEL];
    ((float4*)cl)[t] = ((const float4*)(cc + (size_t)b * D_MODEL))[t];
    __syncthreads();
    int n = nc * 256 + t;
    const float* w = Wo + n;
    float acc = 0.f;
#pragma unroll 8
    for (int m = 0; m < D_MODEL; ++m) acc = fmaf(cl[m], w[(size_t)m * D_MODEL], acc);
    float r = acc + bo[n];
    out[(size_t)b * D_MODEL + n] = r > 0.f ? r : 0.f;
}

extern "C" void kernel_launch(void* const* d_in, const int* in_sizes, int n_in,
                              void* d_out, int out_size, void* d_ws, size_t ws_size,
                              hipStream_t stream) {
    const float* q  = (const float*)d_in[0];
    const float* k  = (const float*)d_in[1];
    const float* v  = (const float*)d_in[2];
    const float* Wq = (const float*)d_in[3];
    const float* bq = (const float*)d_in[4];
    const float* Wk = (const float*)d_in[5];
    // d_in[6] = bk: unused — softmax is shift-invariant, qh.bk is constant per (b,h) row
    const float* Wv = (const float*)d_in[7];
    const float* bv = (const float*)d_in[8];
    const float* Wo = (const float*)d_in[9];
    const float* bo = (const float*)d_in[10];
    float* out = (float*)d_out;

    float* ws = (float*)d_ws;
    float* qh   = ws;                       // 65536
    float* qt   = qh + 65536;               // 1048576
    float* sc   = qt + 1048576;             // 2097152
    float* part = sc + 2097152;             // 8388608
    float* cc   = part + 8388608;           // 65536   (total ~46.7 MB)

    k_qh<<<256, 256, 0, stream>>>(q, Wq, bq, qh);
    k_qtil<<<1024, 256, 0, stream>>>(qh, Wk, qt);
    k_scores<<<512, 256, 0, stream>>>(k, qt, sc);
    k_softmax<<<1024, 256, 0, stream>>>(sc);
    k_av<<<512, 256, 0, stream>>>(v, sc, part);
    k_cc<<<1024, 64, 0, stream>>>(part, Wv, bv, cc);
    k_out<<<256, 256, 0, stream>>>(cc, Wo, bo, out);
}

// Round 4
// 510.893 us; speedup vs baseline: 1.2608x; 1.2608x over previous
//
#include <hip/hip_runtime.h>
#include <math.h>

#define D_MODEL 1024
#define N_HEADS 16
#define D_K 64
#define B_SZ 64
#define S_LEN 2048

// ---------------- kernel 0: qh[b,n] = q[b,:] @ Wq[:,n] + bq[n] ----------------
// grid 256 = (64 b x 4 n-chunks), block 256
__global__ __launch_bounds__(256) void k_qh(const float* __restrict__ q,
                                            const float* __restrict__ Wq,
                                            const float* __restrict__ bq,
                                            float* __restrict__ qh) {
    int b = blockIdx.x >> 2;
    int nc = blockIdx.x & 3;
    int t = threadIdx.x;
    __shared__ float ql[D_MODEL];
    ((float4*)ql)[t] = ((const float4*)(q + (size_t)b * D_MODEL))[t];
    __syncthreads();
    int n = nc * 256 + t;
    const float* w = Wq + n;
    float acc = 0.f;
#pragma unroll 8
    for (int d = 0; d < D_MODEL; ++d) acc = fmaf(ql[d], w[(size_t)d * D_MODEL], acc);
    qh[(size_t)b * D_MODEL + n] = acc + bq[n];
}

// ---------------- kernel 1: qt[b,h,d] = (1/8) * sum_j qh[b,h*64+j] * Wk[d, h*64+j] ----------------
// grid 1024 = (b,h), block 256; thread covers d = t + 256p
__global__ __launch_bounds__(256) void k_qtil(const float* __restrict__ qh,
                                              const float* __restrict__ Wk,
                                              float* __restrict__ qt) {
    int b = blockIdx.x >> 4;
    int h = blockIdx.x & 15;
    int t = threadIdx.x;
    __shared__ float qhl[D_K];
    if (t < 16) ((float4*)qhl)[t] = ((const float4*)(qh + (size_t)b * D_MODEL + h * D_K))[t];
    __syncthreads();
#pragma unroll
    for (int p = 0; p < 4; ++p) {
        int d = p * 256 + t;
        const float* w = Wk + (size_t)d * D_MODEL + h * D_K;
        float acc = 0.f;
#pragma unroll
        for (int j4 = 0; j4 < 16; ++j4) {
            float4 w4 = ((const float4*)w)[j4];
            float4 q4 = ((const float4*)qhl)[j4];
            acc += w4.x * q4.x + w4.y * q4.y + w4.z * q4.z + w4.w * q4.w;
        }
        qt[((size_t)(b * N_HEADS + h)) * D_MODEL + d] = acc * 0.125f;
    }
}

// ---------------- kernel 2 (fused): scores + per-chunk softmax + attn@v ----------------
// grid 512 = (64 b x 8 s-chunks of 256), block 256 = 4 waves.
// Phase A: verbatim round-0 k_scores loop (acc[i][j]: s = s0+64i+lane, head 4w+j).
// Phase B: per-wave shuffle softmax over the chunk; P -> al[h][256]; (m,l) -> ml.
// Phase C: verbatim round-0 k_av body on al; part left UNSCALED (combined in k_cc).
#define ST 256
#define DC 32
#define KROW 36  // 32 + 4 pad: conflict-free b128 reads (quad = 9*row % 8)
__global__ __launch_bounds__(256) void k_attn(const float* __restrict__ k,
                                              const float* __restrict__ v,
                                              const float* __restrict__ qt,
                                              float* __restrict__ part,
                                              float* __restrict__ ml) {
    __shared__ float kt[ST * KROW];          // 36 KB
    __shared__ float qtl[N_HEADS * DC];      // 2 KB
    __shared__ float al[N_HEADS * 256];      // 16 KB  (total 55 KB -> 2 blocks/CU)
    int b = blockIdx.x >> 3;
    int ch = blockIdx.x & 7;
    int t = threadIdx.x;
    int w = t >> 6, lane = t & 63;
    int s0 = ch * ST;
    const float* kbase = k + ((size_t)b * S_LEN + s0) * D_MODEL;
    const float* qtbase = qt + (size_t)b * N_HEADS * D_MODEL;
    // ---- Phase A: scores (verbatim round-0) ----
    float acc[4][4] = {};
    for (int dc = 0; dc < D_MODEL; dc += DC) {
#pragma unroll
        for (int p = 0; p < 8; ++p) {
            int idx = t + 256 * p;
            int s = idx >> 3, d4 = idx & 7;
            float4 v4 = *(const float4*)(kbase + (size_t)s * D_MODEL + dc + 4 * d4);
            *(float4*)(kt + s * KROW + 4 * d4) = v4;
        }
        if (t < 128) {
            int h = t >> 3, d4 = t & 7;
            *(float4*)(qtl + h * DC + 4 * d4) =
                *(const float4*)(qtbase + (size_t)h * D_MODEL + dc + 4 * d4);
        }
        __syncthreads();
#pragma unroll
        for (int d4 = 0; d4 < DC / 4; ++d4) {
            float4 qv[4], kv[4];
#pragma unroll
            for (int j = 0; j < 4; ++j) qv[j] = *(const float4*)(qtl + (4 * w + j) * DC + 4 * d4);
#pragma unroll
            for (int i = 0; i < 4; ++i) kv[i] = *(const float4*)(kt + (64 * i + lane) * KROW + 4 * d4);
#pragma unroll
            for (int i = 0; i < 4; ++i)
#pragma unroll
                for (int j = 0; j < 4; ++j)
                    acc[i][j] = fmaf(kv[i].x, qv[j].x,
                                fmaf(kv[i].y, qv[j].y,
                                fmaf(kv[i].z, qv[j].z,
                                fmaf(kv[i].w, qv[j].w, acc[i][j]))));
        }
        __syncthreads();
    }
    // ---- Phase B: per-chunk softmax for heads 4w..4w+3 ----
#pragma unroll
    for (int j = 0; j < 4; ++j) {
        float mx = fmaxf(fmaxf(acc[0][j], acc[1][j]), fmaxf(acc[2][j], acc[3][j]));
#pragma unroll
        for (int o = 32; o; o >>= 1) mx = fmaxf(mx, __shfl_xor(mx, o, 64));
        float p0 = __expf(acc[0][j] - mx);
        float p1 = __expf(acc[1][j] - mx);
        float p2 = __expf(acc[2][j] - mx);
        float p3 = __expf(acc[3][j] - mx);
        float l = p0 + p1 + p2 + p3;
#pragma unroll
        for (int o = 32; o; o >>= 1) l += __shfl_xor(l, o, 64);
        int h = 4 * w + j;
        al[h * 256 + lane] = p0;          // s = 64*0 + lane
        al[h * 256 + 64 + lane] = p1;
        al[h * 256 + 128 + lane] = p2;
        al[h * 256 + 192 + lane] = p3;
        if (lane == 0) {
            size_t mi = (((size_t)ch * B_SZ + b) * N_HEADS + h) * 2;
            ml[mi] = mx;
            ml[mi + 1] = l;
        }
    }
    __syncthreads();
    // ---- Phase C: attn @ v (verbatim round-0 k_av body) ----
    float4 acc4[N_HEADS];
#pragma unroll
    for (int h = 0; h < N_HEADS; ++h) acc4[h] = make_float4(0.f, 0.f, 0.f, 0.f);
    const float* vbase = v + ((size_t)b * S_LEN + s0) * D_MODEL + 4 * t;
    for (int sg = 0; sg < 64; ++sg) {
        float4 v0 = *(const float4*)(vbase + (size_t)(4 * sg + 0) * D_MODEL);
        float4 v1 = *(const float4*)(vbase + (size_t)(4 * sg + 1) * D_MODEL);
        float4 v2 = *(const float4*)(vbase + (size_t)(4 * sg + 2) * D_MODEL);
        float4 v3 = *(const float4*)(vbase + (size_t)(4 * sg + 3) * D_MODEL);
#pragma unroll
        for (int h = 0; h < N_HEADS; ++h) {
            float4 a4 = *(const float4*)(al + h * 256 + 4 * sg);  // broadcast read
            acc4[h].x = fmaf(a4.x, v0.x, fmaf(a4.y, v1.x, fmaf(a4.z, v2.x, fmaf(a4.w, v3.x, acc4[h].x))));
            acc4[h].y = fmaf(a4.x, v0.y, fmaf(a4.y, v1.y, fmaf(a4.z, v2.y, fmaf(a4.w, v3.y, acc4[h].y))));
            acc4[h].z = fmaf(a4.x, v0.z, fmaf(a4.y, v1.z, fmaf(a4.z, v2.z, fmaf(a4.w, v3.z, acc4[h].z))));
            acc4[h].w = fmaf(a4.x, v0.w, fmaf(a4.y, v1.w, fmaf(a4.z, v2.w, fmaf(a4.w, v3.w, acc4[h].w))));
        }
    }
#pragma unroll
    for (int h = 0; h < N_HEADS; ++h)
        *(float4*)(part + (((size_t)ch * B_SZ + b) * N_HEADS + h) * D_MODEL + 4 * t) = acc4[h];
}

// ---------------- kernel 3: combine chunks (exact flash identity) + Wv projection ----------------
// grid 1024 = (b,h), block 64 (1 wave)
// vt[d] = (1/L) * sum_ch e^{m_ch - M} * part[ch][d],  M = max_ch m_ch, L = sum_ch l_ch e^{m_ch - M}
__global__ __launch_bounds__(64) void k_cc(const float* __restrict__ part,
                                           const float* __restrict__ ml,
                                           const float* __restrict__ Wv,
                                           const float* __restrict__ bv,
                                           float* __restrict__ cc) {
    int b = blockIdx.x >> 4, h = blockIdx.x & 15;
    int lane = threadIdx.x;
    float m8[8], l8[8];
#pragma unroll
    for (int ch = 0; ch < 8; ++ch) {
        size_t mi = (((size_t)ch * B_SZ + b) * N_HEADS + h) * 2;  // uniform -> scalar loads
        m8[ch] = ml[mi];
        l8[ch] = ml[mi + 1];
    }
    float M = m8[0];
#pragma unroll
    for (int ch = 1; ch < 8; ++ch) M = fmaxf(M, m8[ch]);
    float wgt[8];
    float L = 0.f;
#pragma unroll
    for (int ch = 0; ch < 8; ++ch) {
        wgt[ch] = __expf(m8[ch] - M);
        L = fmaf(l8[ch], wgt[ch], L);
    }
    float invL = 1.0f / L;
    __shared__ float vt[D_MODEL];
#pragma unroll
    for (int p = 0; p < 4; ++p) {
        int i4 = lane + 64 * p;
        float4 s = make_float4(0.f, 0.f, 0.f, 0.f);
#pragma unroll
        for (int ch = 0; ch < 8; ++ch) {
            float4 x = *(const float4*)(part + (((size_t)ch * B_SZ + b) * N_HEADS + h) * D_MODEL + 4 * i4);
            s.x = fmaf(wgt[ch], x.x, s.x);
            s.y = fmaf(wgt[ch], x.y, s.y);
            s.z = fmaf(wgt[ch], x.z, s.z);
            s.w = fmaf(wgt[ch], x.w, s.w);
        }
        s.x *= invL; s.y *= invL; s.z *= invL; s.w *= invL;
        *(float4*)(vt + 4 * i4) = s;
    }
    __syncthreads();
    const float* wv = Wv + h * D_K + lane;
    float acc = 0.f;
#pragma unroll 8
    for (int d = 0; d < D_MODEL; ++d) acc = fmaf(vt[d], wv[(size_t)d * D_MODEL], acc);
    cc[(size_t)b * D_MODEL + h * D_K + lane] = acc + bv[h * D_K + lane];
}

// ---------------- kernel 4: out[b,n] = relu(cc[b,:] @ Wo[:,n] + bo[n]) ----------------
// grid 256 = (64 b x 4 n-chunks), block 256
__global__ __launch_bounds__(256) void k_out(const float* __restrict__ cc,
                                             const float* __restrict__ Wo,
                                             const float* __restrict__ bo,
                                             float* __restrict__ out) {
    int b = blockIdx.x >> 2, nc = blockIdx.x & 3;
    int t = threadIdx.x;
    __shared__ float cl[D_MODEL];
    ((float4*)cl)[t] = ((const float4*)(cc + (size_t)b * D_MODEL))[t];
    __syncthreads();
    int n = nc * 256 + t;
    const float* w = Wo + n;
    float acc = 0.f;
#pragma unroll 8
    for (int m = 0; m < D_MODEL; ++m) acc = fmaf(cl[m], w[(size_t)m * D_MODEL], acc);
    float r = acc + bo[n];
    out[(size_t)b * D_MODEL + n] = r > 0.f ? r : 0.f;
}

extern "C" void kernel_launch(void* const* d_in, const int* in_sizes, int n_in,
                              void* d_out, int out_size, void* d_ws, size_t ws_size,
                              hipStream_t stream) {
    const float* q  = (const float*)d_in[0];
    const float* k  = (const float*)d_in[1];
    const float* v  = (const float*)d_in[2];
    const float* Wq = (const float*)d_in[3];
    const float* bq = (const float*)d_in[4];
    const float* Wk = (const float*)d_in[5];
    // d_in[6] = bk: unused — softmax is shift-invariant, qh.bk is constant per (b,h) row
    const float* Wv = (const float*)d_in[7];
    const float* bv = (const float*)d_in[8];
    const float* Wo = (const float*)d_in[9];
    const float* bo = (const float*)d_in[10];
    float* out = (float*)d_out;

    float* ws = (float*)d_ws;
    float* qh   = ws;                       // 65536 floats
    float* qt   = qh + 65536;               // 1048576
    float* part = qt + 1048576;             // 8388608
    float* ml   = part + 8388608;           // 16384  (8 chunks x 64 b x 16 h x {m,l})
    float* cc   = ml + 16384;               // 65536  (total ~38.3 MB)

    k_qh<<<256, 256, 0, stream>>>(q, Wq, bq, qh);
    k_qtil<<<1024, 256, 0, stream>>>(qh, Wk, qt);
    k_attn<<<512, 256, 0, stream>>>(k, v, qt, part, ml);
    k_cc<<<1024, 64, 0, stream>>>(part, ml, Wv, bv, cc);
    k_out<<<256, 256, 0, stream>>>(cc, Wo, bo, out);
}

// Round 5
// 330.702 us; speedup vs baseline: 1.9478x; 1.5449x over previous
//
#include <hip/hip_runtime.h>
#include <math.h>

#define D_MODEL 1024
#define N_HEADS 16
#define D_K 64
#define B_SZ 64
#define S_LEN 2048

// ---------------- kernel 0 (fused q-projection): qt[b,h,d] = (1/8) * sum_j (q[b]@Wq + bq)[h*64+j] * Wk[d, h*64+j] ----------------
// grid 1024 = (b,h), block 256.
// Phase A: qh slice (64 vals) = q[b,:] @ Wq[:,h*64..+63] + bq  — f4 weight loads, 16 d-groups, LDS reduce.
// Phase B: verbatim old k_qtil body on the in-LDS slice.
__global__ __launch_bounds__(256) void k_qproj(const float* __restrict__ q,
                                               const float* __restrict__ Wq,
                                               const float* __restrict__ bq,
                                               const float* __restrict__ Wk,
                                               float* __restrict__ qt) {
    int b = blockIdx.x >> 4, h = blockIdx.x & 15;
    int t = threadIdx.x;
    __shared__ float ql[D_MODEL];
    __shared__ float qsl[D_K];
    __shared__ float4 red[256];
    ((float4*)ql)[t] = ((const float4*)(q + (size_t)b * D_MODEL))[t];
    __syncthreads();
    // Phase A
    int j4 = t & 15, dg = t >> 4;
    float4 a = make_float4(0.f, 0.f, 0.f, 0.f);
#pragma unroll 8
    for (int i = 0; i < 64; ++i) {
        int d = i * 16 + dg;  // interleaved: wave's 4 dg values hit 4 distinct LDS banks
        float4 w4 = *(const float4*)(Wq + (size_t)d * D_MODEL + h * D_K + 4 * j4);
        float s = ql[d];
        a.x = fmaf(s, w4.x, a.x);
        a.y = fmaf(s, w4.y, a.y);
        a.z = fmaf(s, w4.z, a.z);
        a.w = fmaf(s, w4.w, a.w);
    }
    red[t] = a;
    __syncthreads();
    if (t < 16) {
        float4 r = make_float4(0.f, 0.f, 0.f, 0.f);
#pragma unroll
        for (int g = 0; g < 16; ++g) {
            float4 x = red[g * 16 + t];
            r.x += x.x; r.y += x.y; r.z += x.z; r.w += x.w;
        }
        float4 bb = *(const float4*)(bq + h * D_K + 4 * t);
        r.x += bb.x; r.y += bb.y; r.z += bb.z; r.w += bb.w;
        *(float4*)(qsl + 4 * t) = r;
    }
    __syncthreads();
    // Phase B (verbatim old k_qtil inner)
#pragma unroll
    for (int p = 0; p < 4; ++p) {
        int d = p * 256 + t;
        const float* w = Wk + (size_t)d * D_MODEL + h * D_K;
        float acc = 0.f;
#pragma unroll
        for (int j4i = 0; j4i < 16; ++j4i) {
            float4 w4 = ((const float4*)w)[j4i];
            float4 q4 = ((const float4*)qsl)[j4i];
            acc += w4.x * q4.x + w4.y * q4.y + w4.z * q4.z + w4.w * q4.w;
        }
        qt[((size_t)(b * N_HEADS + h)) * D_MODEL + d] = acc * 0.125f;
    }
}

// ---------------- kernel 1 (fused, FROZEN from round 4): scores + per-chunk softmax + attn@v ----------------
// grid 512 = (64 b x 8 s-chunks of 256), block 256 = 4 waves.
#define ST 256
#define DC 32
#define KROW 36  // 32 + 4 pad: conflict-free b128 reads (quad = 9*row % 8)
__global__ __launch_bounds__(256) void k_attn(const float* __restrict__ k,
                                              const float* __restrict__ v,
                                              const float* __restrict__ qt,
                                              float* __restrict__ part,
                                              float* __restrict__ ml) {
    __shared__ float kt[ST * KROW];          // 36 KB
    __shared__ float qtl[N_HEADS * DC];      // 2 KB
    __shared__ float al[N_HEADS * 256];      // 16 KB  (total 55 KB -> 2 blocks/CU)
    int b = blockIdx.x >> 3;
    int ch = blockIdx.x & 7;
    int t = threadIdx.x;
    int w = t >> 6, lane = t & 63;
    int s0 = ch * ST;
    const float* kbase = k + ((size_t)b * S_LEN + s0) * D_MODEL;
    const float* qtbase = qt + (size_t)b * N_HEADS * D_MODEL;
    // ---- Phase A: scores ----
    float acc[4][4] = {};
    for (int dc = 0; dc < D_MODEL; dc += DC) {
#pragma unroll
        for (int p = 0; p < 8; ++p) {
            int idx = t + 256 * p;
            int s = idx >> 3, d4 = idx & 7;
            float4 v4 = *(const float4*)(kbase + (size_t)s * D_MODEL + dc + 4 * d4);
            *(float4*)(kt + s * KROW + 4 * d4) = v4;
        }
        if (t < 128) {
            int hh = t >> 3, d4 = t & 7;
            *(float4*)(qtl + hh * DC + 4 * d4) =
                *(const float4*)(qtbase + (size_t)hh * D_MODEL + dc + 4 * d4);
        }
        __syncthreads();
#pragma unroll
        for (int d4 = 0; d4 < DC / 4; ++d4) {
            float4 qv[4], kv[4];
#pragma unroll
            for (int j = 0; j < 4; ++j) qv[j] = *(const float4*)(qtl + (4 * w + j) * DC + 4 * d4);
#pragma unroll
            for (int i = 0; i < 4; ++i) kv[i] = *(const float4*)(kt + (64 * i + lane) * KROW + 4 * d4);
#pragma unroll
            for (int i = 0; i < 4; ++i)
#pragma unroll
                for (int j = 0; j < 4; ++j)
                    acc[i][j] = fmaf(kv[i].x, qv[j].x,
                                fmaf(kv[i].y, qv[j].y,
                                fmaf(kv[i].z, qv[j].z,
                                fmaf(kv[i].w, qv[j].w, acc[i][j]))));
        }
        __syncthreads();
    }
    // ---- Phase B: per-chunk softmax for heads 4w..4w+3 ----
#pragma unroll
    for (int j = 0; j < 4; ++j) {
        float mx = fmaxf(fmaxf(acc[0][j], acc[1][j]), fmaxf(acc[2][j], acc[3][j]));
#pragma unroll
        for (int o = 32; o; o >>= 1) mx = fmaxf(mx, __shfl_xor(mx, o, 64));
        float p0 = __expf(acc[0][j] - mx);
        float p1 = __expf(acc[1][j] - mx);
        float p2 = __expf(acc[2][j] - mx);
        float p3 = __expf(acc[3][j] - mx);
        float l = p0 + p1 + p2 + p3;
#pragma unroll
        for (int o = 32; o; o >>= 1) l += __shfl_xor(l, o, 64);
        int h = 4 * w + j;
        al[h * 256 + lane] = p0;
        al[h * 256 + 64 + lane] = p1;
        al[h * 256 + 128 + lane] = p2;
        al[h * 256 + 192 + lane] = p3;
        if (lane == 0) {
            size_t mi = (((size_t)ch * B_SZ + b) * N_HEADS + h) * 2;
            ml[mi] = mx;
            ml[mi + 1] = l;
        }
    }
    __syncthreads();
    // ---- Phase C: attn @ v ----
    float4 acc4[N_HEADS];
#pragma unroll
    for (int h = 0; h < N_HEADS; ++h) acc4[h] = make_float4(0.f, 0.f, 0.f, 0.f);
    const float* vbase = v + ((size_t)b * S_LEN + s0) * D_MODEL + 4 * t;
    for (int sg = 0; sg < 64; ++sg) {
        float4 v0 = *(const float4*)(vbase + (size_t)(4 * sg + 0) * D_MODEL);
        float4 v1 = *(const float4*)(vbase + (size_t)(4 * sg + 1) * D_MODEL);
        float4 v2 = *(const float4*)(vbase + (size_t)(4 * sg + 2) * D_MODEL);
        float4 v3 = *(const float4*)(vbase + (size_t)(4 * sg + 3) * D_MODEL);
#pragma unroll
        for (int h = 0; h < N_HEADS; ++h) {
            float4 a4 = *(const float4*)(al + h * 256 + 4 * sg);  // broadcast read
            acc4[h].x = fmaf(a4.x, v0.x, fmaf(a4.y, v1.x, fmaf(a4.z, v2.x, fmaf(a4.w, v3.x, acc4[h].x))));
            acc4[h].y = fmaf(a4.x, v0.y, fmaf(a4.y, v1.y, fmaf(a4.z, v2.y, fmaf(a4.w, v3.y, acc4[h].y))));
            acc4[h].z = fmaf(a4.x, v0.z, fmaf(a4.y, v1.z, fmaf(a4.z, v2.z, fmaf(a4.w, v3.z, acc4[h].z))));
            acc4[h].w = fmaf(a4.x, v0.w, fmaf(a4.y, v1.w, fmaf(a4.z, v2.w, fmaf(a4.w, v3.w, acc4[h].w))));
        }
    }
#pragma unroll
    for (int h = 0; h < N_HEADS; ++h)
        *(float4*)(part + (((size_t)ch * B_SZ + b) * N_HEADS + h) * D_MODEL + 4 * t) = acc4[h];
}

// ---------------- kernel 2: flash-combine chunks + Wv projection ----------------
// grid 1024 = (b,h), block 256 (was 1 wave).
// vt[d] = (1/L) * sum_ch e^{m_ch-M} part[ch][d]; then cc slice = vt @ Wv[:,h-slice] + bv.
__global__ __launch_bounds__(256) void k_cc(const float* __restrict__ part,
                                            const float* __restrict__ ml,
                                            const float* __restrict__ Wv,
                                            const float* __restrict__ bv,
                                            float* __restrict__ cc) {
    int b = blockIdx.x >> 4, h = blockIdx.x & 15;
    int t = threadIdx.x;
    __shared__ float vt[D_MODEL];
    __shared__ float4 red[256];
    float m8[8], l8[8];
#pragma unroll
    for (int ch = 0; ch < 8; ++ch) {
        size_t mi = (((size_t)ch * B_SZ + b) * N_HEADS + h) * 2;  // uniform -> scalar loads
        m8[ch] = ml[mi];
        l8[ch] = ml[mi + 1];
    }
    float M = m8[0];
#pragma unroll
    for (int ch = 1; ch < 8; ++ch) M = fmaxf(M, m8[ch]);
    float wgt[8];
    float L = 0.f;
#pragma unroll
    for (int ch = 0; ch < 8; ++ch) {
        wgt[ch] = __expf(m8[ch] - M);
        L = fmaf(l8[ch], wgt[ch], L);
    }
    float invL = 1.0f / L;
    // Phase 1: vt (256 threads x f4 = full 1024 row)
    float4 s = make_float4(0.f, 0.f, 0.f, 0.f);
#pragma unroll
    for (int ch = 0; ch < 8; ++ch) {
        float4 x = *(const float4*)(part + (((size_t)ch * B_SZ + b) * N_HEADS + h) * D_MODEL + 4 * t);
        s.x = fmaf(wgt[ch], x.x, s.x);
        s.y = fmaf(wgt[ch], x.y, s.y);
        s.z = fmaf(wgt[ch], x.z, s.z);
        s.w = fmaf(wgt[ch], x.w, s.w);
    }
    s.x *= invL; s.y *= invL; s.z *= invL; s.w *= invL;
    *(float4*)(vt + 4 * t) = s;
    __syncthreads();
    // Phase 2: cc[b, h*64 + 4*j4 ..] ; f4 weight loads, interleaved d-groups
    int j4 = t & 15, dg = t >> 4;
    float4 a = make_float4(0.f, 0.f, 0.f, 0.f);
#pragma unroll 8
    for (int i = 0; i < 64; ++i) {
        int d = i * 16 + dg;  // wave's 4 dg -> 4 distinct banks on vt[d]
        float4 w4 = *(const float4*)(Wv + (size_t)d * D_MODEL + h * D_K + 4 * j4);
        float sv = vt[d];
        a.x = fmaf(sv, w4.x, a.x);
        a.y = fmaf(sv, w4.y, a.y);
        a.z = fmaf(sv, w4.z, a.z);
        a.w = fmaf(sv, w4.w, a.w);
    }
    red[t] = a;
    __syncthreads();
    if (t < 16) {
        float4 r = make_float4(0.f, 0.f, 0.f, 0.f);
#pragma unroll
        for (int g = 0; g < 16; ++g) {
            float4 x = red[g * 16 + t];
            r.x += x.x; r.y += x.y; r.z += x.z; r.w += x.w;
        }
        float4 bb = *(const float4*)(bv + h * D_K + 4 * t);
        r.x += bb.x; r.y += bb.y; r.z += bb.z; r.w += bb.w;
        *(float4*)(cc + (size_t)b * D_MODEL + h * D_K + 4 * t) = r;
    }
}

// ---------------- kernel 3: out[b,n] = relu(cc[b,:] @ Wo[:,n] + bo[n]) ----------------
// grid 256 = (64 b x 4 n-chunks), block 256; f4 weight loads (1 KB/wave contiguous), 4 wave-d-groups.
__global__ __launch_bounds__(256) void k_out(const float* __restrict__ cc,
                                             const float* __restrict__ Wo,
                                             const float* __restrict__ bo,
                                             float* __restrict__ out) {
    int b = blockIdx.x >> 2, nc = blockIdx.x & 3;
    int t = threadIdx.x;
    __shared__ float cl[D_MODEL];
    __shared__ float4 red[256];
    ((float4*)cl)[t] = ((const float4*)(cc + (size_t)b * D_MODEL))[t];
    __syncthreads();
    int n4 = t & 63, dg = t >> 6;  // dg == wave id -> cl[d] is wave-uniform broadcast
    float4 a = make_float4(0.f, 0.f, 0.f, 0.f);
#pragma unroll 8
    for (int i = 0; i < 256; ++i) {
        int d = dg * 256 + i;
        float4 w4 = *(const float4*)(Wo + (size_t)d * D_MODEL + nc * 256 + 4 * n4);
        float s = cl[d];
        a.x = fmaf(s, w4.x, a.x);
        a.y = fmaf(s, w4.y, a.y);
        a.z = fmaf(s, w4.z, a.z);
        a.w = fmaf(s, w4.w, a.w);
    }
    red[t] = a;
    __syncthreads();
    if (t < 64) {
        float4 r = red[t];
#pragma unroll
        for (int g = 1; g < 4; ++g) {
            float4 x = red[g * 64 + t];
            r.x += x.x; r.y += x.y; r.z += x.z; r.w += x.w;
        }
        float4 bb = *(const float4*)(bo + nc * 256 + 4 * t);
        r.x += bb.x; r.y += bb.y; r.z += bb.z; r.w += bb.w;
        r.x = r.x > 0.f ? r.x : 0.f;
        r.y = r.y > 0.f ? r.y : 0.f;
        r.z = r.z > 0.f ? r.z : 0.f;
        r.w = r.w > 0.f ? r.w : 0.f;
        *(float4*)(out + (size_t)b * D_MODEL + nc * 256 + 4 * t) = r;
    }
}

extern "C" void kernel_launch(void* const* d_in, const int* in_sizes, int n_in,
                              void* d_out, int out_size, void* d_ws, size_t ws_size,
                              hipStream_t stream) {
    const float* q  = (const float*)d_in[0];
    const float* k  = (const float*)d_in[1];
    const float* v  = (const float*)d_in[2];
    const float* Wq = (const float*)d_in[3];
    const float* bq = (const float*)d_in[4];
    const float* Wk = (const float*)d_in[5];
    // d_in[6] = bk: unused — softmax is shift-invariant, qh.bk is constant per (b,h) row
    const float* Wv = (const float*)d_in[7];
    const float* bv = (const float*)d_in[8];
    const float* Wo = (const float*)d_in[9];
    const float* bo = (const float*)d_in[10];
    float* out = (float*)d_out;

    float* ws = (float*)d_ws;
    float* qt   = ws;                       // 1048576 floats
    float* part = qt + 1048576;             // 8388608
    float* ml   = part + 8388608;           // 16384
    float* cc   = ml + 16384;               // 65536   (total ~38 MB)

    k_qproj<<<1024, 256, 0, stream>>>(q, Wq, bq, Wk, qt);
    k_attn<<<512, 256, 0, stream>>>(k, v, qt, part, ml);
    k_cc<<<1024, 256, 0, stream>>>(part, ml, Wv, bv, cc);
    k_out<<<256, 256, 0, stream>>>(cc, Wo, bo, out);
}